// Round 1
// 326.216 us; speedup vs baseline: 1.0178x; 1.0178x over previous
//
#include <hip/hip_runtime.h>
#include <stdint.h>

// Problem constants (static shapes from the reference)
constexpr int Bq = 2;
constexpr int Qn = 300;
constexpr int Cn = 80;
constexpr int Kn = 300;
constexpr int NFLAT = Qn * Cn;   // 24000
constexpr int MHs = 128;
constexpr int MWs = 128;
constexpr int THs = 320;
constexpr int TWs = 320;

// Output layout (flat concatenation in reference return order, all as float)
constexpr int OFF_SCORES = 0;                         // [B,K]     600
constexpr int OFF_LABELS = Bq * Kn;                   // [B,K]     600
constexpr int OFF_BOXES  = 2 * Bq * Kn;               // [B,K,4]   2400
constexpr int OFF_MASKS  = 2 * Bq * Kn + Bq * Kn * 4; // [B,K,320,320]

constexpr int TPB = 1024;
constexpr int EPT = (NFLAT + TPB - 1) / TPB;          // 24 elements/thread

typedef float vf4  __attribute__((ext_vector_type(4)));              // 16B-aligned
typedef float uvf4 __attribute__((ext_vector_type(4), aligned(4)));  // align-4 load

// ---------------------------------------------------------------------------
// Kernel A v7: bisection with ONE barrier per iteration and zero atomics in
// the loop. lo/hi/done live in registers in every thread (updates are uniform
// functions of the block-wide count, so all threads stay consistent). Per-wave
// counts go to a parity-double-buffered LDS array (16 ints); each thread sums
// all 16 after a single barrier. hi starts at 0x3F800000 (sigmoid <= 1.0 =>
// count(key>hi)==0 < K, invariant intact) to skip the dead exponent-narrowing
// iterations. Candidate collection + exact ranking identical to v5 (proven:
// unique 64-bit keys (bits<<32)|~idx reproduce jax.lax.top_k order).
// ---------------------------------------------------------------------------
__global__ __launch_bounds__(TPB) void topk_kernel(
    const float* __restrict__ logits,   // [B,Q,C]
    const float* __restrict__ boxes,    // [B,Q,4] cxcywh
    const float* __restrict__ osz,      // [B,2] (w,h)
    float* __restrict__ out,
    int* __restrict__ qidx_ws)          // [B,K]
{
    const int b    = blockIdx.x;
    const int tid  = threadIdx.x;
    const int wave = tid >> 6;          // 16 waves
    const float* lg = logits + (size_t)b * NFLAT;

    uint32_t key[EPT];
    #pragma unroll
    for (int j = 0; j < EPT; ++j) {
        int idx = j * TPB + tid;
        bool valid = (idx < NFLAT);
        float x = valid ? lg[idx] : 0.0f;
        float s = 1.0f / (1.0f + expf(-x));   // keep formula: matched ref rounds 1-5
        key[j] = valid ? __float_as_uint(s) : 0u;
    }

    __shared__ int cnt[2][16];
    __shared__ int sh_cnt;
    __shared__ unsigned long long sk[1024];
    if (tid == 0) sh_cnt = 0;           // published by the loop's first barrier

    // Bisection invariant: count(key > lo) >= K > count(key > hi)
    uint32_t lo = 0u, hi = 0x3F800000u;
    for (int it = 0; it < 32 && (hi - lo) > 1u; ++it) {
        const uint32_t mid = lo + ((hi - lo) >> 1);
        int c = 0;
        #pragma unroll
        for (int j = 0; j < EPT; ++j) c += (key[j] > mid) ? 1 : 0;
        #pragma unroll
        for (int off = 32; off > 0; off >>= 1) c += __shfl_down(c, off);
        if ((tid & 63) == 0) cnt[it & 1][wave] = c;
        __syncthreads();
        int total = 0;
        #pragma unroll
        for (int w = 0; w < 16; ++w) total += cnt[it & 1][w];
        // uniform update in every thread — no tid0 round-trip, no 2nd barrier
        if (total >= Kn) { lo = mid; if (total <= 768) break; }
        else             { hi = mid; }
        // parity buffer makes the next iteration's writes WAR-safe: a wave
        // cannot reach cnt[it&1] again without crossing the next barrier.
    }

    // Collect candidates: key > T  (strictly; count >= K guaranteed)
    const uint32_t T = lo;
    #pragma unroll
    for (int j = 0; j < EPT; ++j) {
        int idx = j * TPB + tid;
        if (idx < NFLAT && key[j] > T) {
            int p = atomicAdd(&sh_cnt, 1);
            if (p < 1024)
                sk[p] = ((unsigned long long)key[j] << 32)
                      | (unsigned long long)(0xFFFFFFFFu - (uint32_t)idx);
        }
    }
    __syncthreads();

    // Rank by count (unique keys => ranks are a permutation; LDS broadcast)
    const int n = min(sh_cnt, 1024);
    if (tid < n) {
        unsigned long long my = sk[tid];
        int rank = 0;
        for (int i = 0; i < n; ++i) rank += (sk[i] > my) ? 1 : 0;
        if (rank < Kn) {
            uint32_t idx = 0xFFFFFFFFu - (uint32_t)(my & 0xFFFFFFFFull);
            float score  = __uint_as_float((uint32_t)(my >> 32));
            int label = (int)(idx % (uint32_t)Cn);
            int q     = (int)(idx / (uint32_t)Cn);

            out[OFF_SCORES + b * Kn + rank] = score;
            out[OFF_LABELS + b * Kn + rank] = (float)label;

            const float sw = osz[b * 2 + 0];
            const float sh = osz[b * 2 + 1];
            const float* bx = boxes + ((size_t)(b * Qn + q)) * 4;
            float cx = bx[0], cy = bx[1], w = bx[2], h = bx[3];
            float* ob = out + OFF_BOXES + ((size_t)(b * Kn + rank)) * 4;
            ob[0] = (cx - 0.5f * w) * sw;
            ob[1] = (cy - 0.5f * h) * sh;
            ob[2] = (cx + 0.5f * w) * sw;
            ob[3] = (cy + 0.5f * h) * sh;

            qidx_ws[b * Kn + rank] = q;
        }
    }
}

// ---------------------------------------------------------------------------
// Kernel B v6 (unchanged — proven): lane = 4 consecutive output cols; wave
// stores are contiguous 64B-aligned runs -> zero write amplification. All 8
// x-taps for a lane's 4 px fall in a 4-wide source window (span<=3, proven),
// loaded as ONE align-4 dwordx4; x-weights are a per-lane zero-padded 4x4 dot
// table in registers. y uses the period-5 rotation: 2 new source rows per 5
// output rows. Borders by index clamp (sign-preserving => threshold intact).
// ---------------------------------------------------------------------------
__global__ __launch_bounds__(320) void resize_kernel(
    const float* __restrict__ masks,    // [B,Q,128,128]
    const int* __restrict__ qidx_ws,    // [B,K]
    float* __restrict__ out)
{
    const int blk = blockIdx.x;
    const int bk  = blk >> 2;          // b*K + k
    const int s   = blk & 3;           // 80-row chunk
    const int tid = threadIdx.x;
    const int b   = bk / Kn;
    const int q   = qidx_ws[bk];
    const int c   = tid % 80;          // out cols 4c..4c+3
    const int rs  = tid / 80;          // 20-row slab within chunk

    const float* M = masks + ((size_t)(b * Qn + q)) * (MHs * MWs);

    // ---- x setup: source window base s0 and 4x4 zero-padded weight table
    int s0;
    {
        float sx0 = fmaf(0.4f, (float)(4 * c), -0.3f);
        int i0 = (int)floorf(sx0);
        s0 = min(max(i0, 0), MWs - 4);   // [0,124]
    }
    float W[4][4];
    #pragma unroll
    for (int t = 0; t < 4; ++t) {
        int ox = 4 * c + t;
        float sx = fmaf(0.4f, (float)ox, -0.3f);
        int ix0 = (int)floorf(sx);
        float fr = sx - (float)ix0;
        int ca = max(ix0, 0);
        int cb = min(ix0 + 1, MWs - 1);
        float wa = 1.0f - fr, wb = fr;
        #pragma unroll
        for (int j = 0; j < 4; ++j) {
            float w = 0.0f;
            if (s0 + j == ca) w += wa;
            if (s0 + j == cb) w += wb;
            W[t][j] = w;
        }
    }

    auto hrow = [&](float* hv, int r) {
        uvf4 a = *(const uvf4*)(M + r * MWs + s0);
        #pragma unroll
        for (int t = 0; t < 4; ++t)
            hv[t] = fmaf(W[t][0], a[0],
                    fmaf(W[t][1], a[1],
                    fmaf(W[t][2], a[2], W[t][3] * a[3])));
    };

    float* outm = out + OFF_MASKS + (size_t)bk * (THs * TWs);
    auto emit = [&](int row, float wA, const float* pA, float wB, const float* pB) {
        vf4 o;
        #pragma unroll
        for (int t = 0; t < 4; ++t) {
            float v = fmaf(wA, pA[t], wB * pB[t]);
            o[t] = (v > 0.0f) ? 1.0f : 0.0f;
        }
        __builtin_nontemporal_store(o, (vf4*)(outm + (size_t)row * TWs + 4 * c));
    };

    const int Y0 = 80 * s + 20 * rs;   // first output row of this lane
    const int M0 = Y0 / 5;             // 16s + 4rs

    float hA[4], hB[4], hC[4], hD[4];
    hrow(hC, max(2 * M0 - 1, 0));
    hrow(hD, 2 * M0);

    #pragma unroll
    for (int g = 0; g < 4; ++g) {
        #pragma unroll
        for (int t = 0; t < 4; ++t) { hA[t] = hC[t]; hB[t] = hD[t]; }
        const int Mg = M0 + g;
        hrow(hC, 2 * Mg + 1);
        hrow(hD, min(2 * Mg + 2, MHs - 1));

        const int Y = Y0 + 5 * g;
        emit(Y + 0, 0.3f, hA, 0.7f, hB);   // phase 0: h[2m-1], h[2m]
        emit(Y + 1, 0.9f, hB, 0.1f, hC);   // phase 1: h[2m],  h[2m+1]
        emit(Y + 2, 0.5f, hB, 0.5f, hC);   // phase 2
        emit(Y + 3, 0.1f, hB, 0.9f, hC);   // phase 3
        emit(Y + 4, 0.7f, hC, 0.3f, hD);   // phase 4: h[2m+1], h[2m+2]
    }
}

// ---------------------------------------------------------------------------
extern "C" void kernel_launch(void* const* d_in, const int* in_sizes, int n_in,
                              void* d_out, int out_size, void* d_ws, size_t ws_size,
                              hipStream_t stream) {
    const float* logits = (const float*)d_in[0];   // [B,Q,C]
    const float* boxes  = (const float*)d_in[1];   // [B,Q,4]
    const float* masks  = (const float*)d_in[2];   // [B,Q,128,128]
    const float* osz    = (const float*)d_in[3];   // [B,2]
    // d_in[4]/d_in[5] = target_h/target_w (constant 320, baked in)

    float* out = (float*)d_out;
    int* qidx  = (int*)d_ws;                       // B*K ints

    topk_kernel<<<Bq, TPB, 0, stream>>>(logits, boxes, osz, out, qidx);
    resize_kernel<<<Bq * Kn * 4, 320, 0, stream>>>(masks, qidx, out);
}

// Round 2
// 319.909 us; speedup vs baseline: 1.0378x; 1.0197x over previous
//
#include <hip/hip_runtime.h>
#include <stdint.h>

// Problem constants (static shapes from the reference)
constexpr int Bq = 2;
constexpr int Qn = 300;
constexpr int Cn = 80;
constexpr int Kn = 300;
constexpr int NFLAT = Qn * Cn;   // 24000
constexpr int MHs = 128;
constexpr int MWs = 128;
constexpr int THs = 320;
constexpr int TWs = 320;

// Output layout (flat concatenation in reference return order, all as float)
constexpr int OFF_SCORES = 0;                         // [B,K]     600
constexpr int OFF_LABELS = Bq * Kn;                   // [B,K]     600
constexpr int OFF_BOXES  = 2 * Bq * Kn;               // [B,K,4]   2400
constexpr int OFF_MASKS  = 2 * Bq * Kn + Bq * Kn * 4; // [B,K,320,320]

constexpr int TPB = 1024;
constexpr int EPT = (NFLAT + TPB - 1) / TPB;          // 24 elements/thread

typedef float vf4  __attribute__((ext_vector_type(4)));              // 16B-aligned
typedef float uvf4 __attribute__((ext_vector_type(4), aligned(4)));  // align-4 load

// ---------------------------------------------------------------------------
// Kernel A v8: 4-way bisection (3 midpoints per barrier, ~7 iters vs ~13).
// Per-thread counts for the 3 mids packed in ONE uint64 (16-bit fields:
// per-thread <=24, wave sum <=1536, block sum <=24000 — all fit), single
// shuffle-reduce chain, one barrier per iteration, lo/hi in registers
// (updates uniform). Collection uses wave-aggregated LDS atomics (ballot +
// prefix-popcount, 1 atomic per wave per j-slice instead of ~700 serialized
// per-thread atomics). Ranking identical to v5 (proven: unique 64-bit keys
// (bits<<32)|~idx reproduce jax.lax.top_k order exactly).
// ---------------------------------------------------------------------------
__global__ __launch_bounds__(TPB) void topk_kernel(
    const float* __restrict__ logits,   // [B,Q,C]
    const float* __restrict__ boxes,    // [B,Q,4] cxcywh
    const float* __restrict__ osz,      // [B,2] (w,h)
    float* __restrict__ out,
    int* __restrict__ qidx_ws)          // [B,K]
{
    const int b    = blockIdx.x;
    const int tid  = threadIdx.x;
    const int wave = tid >> 6;          // 16 waves
    const int lane = tid & 63;
    const float* lg = logits + (size_t)b * NFLAT;

    uint32_t key[EPT];
    #pragma unroll
    for (int j = 0; j < EPT; ++j) {
        int idx = j * TPB + tid;
        bool valid = (idx < NFLAT);
        float x = valid ? lg[idx] : 0.0f;
        float s = 1.0f / (1.0f + expf(-x));   // keep formula: matched ref rounds 1-5
        key[j] = valid ? __float_as_uint(s) : 0u;
    }

    __shared__ unsigned long long cnt3[2][16];
    __shared__ int sh_cnt;
    __shared__ unsigned long long sk[1024];
    if (tid == 0) sh_cnt = 0;           // published by the loop's first barrier

    // Invariant: count(key > lo) >= K > count(key > hi). sigmoid <= 1.0 =>
    // count(key > 0x3F800000) == 0, so hi starts there (skips exponent range).
    uint32_t lo = 0u, hi = 0x3F800000u;
    for (int it = 0; it < 16; ++it) {
        if (hi - lo <= 3u) break;       // uniform exit (lo/hi uniform)
        const uint32_t step = (hi - lo) >> 2;
        const uint32_t m1 = lo + step, m2 = lo + 2 * step, m3 = lo + 3 * step;
        int c1 = 0, c2 = 0, c3 = 0;
        #pragma unroll
        for (int j = 0; j < EPT; ++j) {
            uint32_t k = key[j];
            c1 += (k > m1) ? 1 : 0;
            c2 += (k > m2) ? 1 : 0;
            c3 += (k > m3) ? 1 : 0;
        }
        unsigned long long p = (unsigned long long)c1
                             | ((unsigned long long)c2 << 16)
                             | ((unsigned long long)c3 << 32);
        #pragma unroll
        for (int off = 32; off > 0; off >>= 1) p += __shfl_down(p, off);
        if (lane == 0) cnt3[it & 1][wave] = p;
        __syncthreads();
        unsigned long long tot = 0;
        #pragma unroll
        for (int w = 0; w < 16; ++w) tot += cnt3[it & 1][w];
        const int n1 = (int)(tot & 0xFFFFull);
        const int n2 = (int)((tot >> 16) & 0xFFFFull);
        const int n3 = (int)((tot >> 32) & 0xFFFFull);
        // uniform bracket update in every thread; counts decrease m1->m3
        if (n3 >= Kn)      { lo = m3;          if (n3 <= 768) break; }
        else if (n2 >= Kn) { lo = m2; hi = m3; if (n2 <= 768) break; }
        else if (n1 >= Kn) { lo = m1; hi = m2; if (n1 <= 768) break; }
        else               { hi = m1; }
        // parity buffer makes next iteration's cnt3 writes WAR-safe: a wave
        // cannot reach cnt3[it&1] again without crossing the next barrier.
    }

    // Collect candidates key > T (strict; count >= K guaranteed by invariant).
    // Wave-aggregated LDS atomic: 1 atomicAdd per wave per slice.
    const uint32_t T = lo;
    #pragma unroll
    for (int j = 0; j < EPT; ++j) {
        int idx = j * TPB + tid;
        bool pred = (idx < NFLAT) && (key[j] > T);
        unsigned long long m = __ballot(pred);
        int base = 0;
        if (lane == 0 && m) base = atomicAdd(&sh_cnt, __popcll(m));
        base = __shfl(base, 0);
        if (pred) {
            int p = base + __popcll(m & ((1ull << lane) - 1ull));
            if (p < 1024)
                sk[p] = ((unsigned long long)key[j] << 32)
                      | (unsigned long long)(0xFFFFFFFFu - (uint32_t)idx);
        }
    }
    __syncthreads();

    // Rank by count (unique keys => ranks are a permutation; LDS broadcast)
    const int n = min(sh_cnt, 1024);
    if (tid < n) {
        unsigned long long my = sk[tid];
        int rank = 0;
        for (int i = 0; i < n; ++i) rank += (sk[i] > my) ? 1 : 0;
        if (rank < Kn) {
            uint32_t idx = 0xFFFFFFFFu - (uint32_t)(my & 0xFFFFFFFFull);
            float score  = __uint_as_float((uint32_t)(my >> 32));
            int label = (int)(idx % (uint32_t)Cn);
            int q     = (int)(idx / (uint32_t)Cn);

            out[OFF_SCORES + b * Kn + rank] = score;
            out[OFF_LABELS + b * Kn + rank] = (float)label;

            const float sw = osz[b * 2 + 0];
            const float sh = osz[b * 2 + 1];
            const float* bx = boxes + ((size_t)(b * Qn + q)) * 4;
            float cx = bx[0], cy = bx[1], w = bx[2], h = bx[3];
            float* ob = out + OFF_BOXES + ((size_t)(b * Kn + rank)) * 4;
            ob[0] = (cx - 0.5f * w) * sw;
            ob[1] = (cy - 0.5f * h) * sh;
            ob[2] = (cx + 0.5f * w) * sw;
            ob[3] = (cy + 0.5f * h) * sh;

            qidx_ws[b * Kn + rank] = q;
        }
    }
}

// ---------------------------------------------------------------------------
// Kernel B v7: same proven math/store layout as v6, regridded to 1200 blocks
// x 2 chunks (same bk => x-setup, W table, mask pointer shared across both).
// 1200 blocks < 1536 resident (6 blocks/CU x 256) => single fully-resident
// scheduling round, no 56%-full tail round, half the dispatch events.
// Lane = 4 consecutive output cols; wave stores contiguous 1KB runs. All 8
// x-taps fall in a 4-wide window (span<=3, proven) loaded as ONE align-4
// dwordx4; y uses the period-5 rotation (2 new source rows per 5 out rows).
// ---------------------------------------------------------------------------
__global__ __launch_bounds__(320) void resize_kernel(
    const float* __restrict__ masks,    // [B,Q,128,128]
    const int* __restrict__ qidx_ws,    // [B,K]
    float* __restrict__ out)
{
    const int blk = blockIdx.x;         // 0..1199
    const int bk  = blk >> 1;           // b*K + k
    const int sP  = (blk & 1) * 2;      // chunk pair: {0,1} or {2,3}
    const int tid = threadIdx.x;
    const int b   = bk / Kn;
    const int q   = qidx_ws[bk];
    const int c   = tid % 80;           // out cols 4c..4c+3
    const int rs  = tid / 80;           // 20-row slab within chunk

    const float* M = masks + ((size_t)(b * Qn + q)) * (MHs * MWs);

    // ---- x setup (independent of chunk s): window base s0, 4x4 weight table
    int s0;
    {
        float sx0 = fmaf(0.4f, (float)(4 * c), -0.3f);
        int i0 = (int)floorf(sx0);
        s0 = min(max(i0, 0), MWs - 4);   // [0,124]
    }
    float W[4][4];
    #pragma unroll
    for (int t = 0; t < 4; ++t) {
        int ox = 4 * c + t;
        float sx = fmaf(0.4f, (float)ox, -0.3f);
        int ix0 = (int)floorf(sx);
        float fr = sx - (float)ix0;
        int ca = max(ix0, 0);
        int cb = min(ix0 + 1, MWs - 1);
        float wa = 1.0f - fr, wb = fr;
        #pragma unroll
        for (int j = 0; j < 4; ++j) {
            float w = 0.0f;
            if (s0 + j == ca) w += wa;
            if (s0 + j == cb) w += wb;
            W[t][j] = w;
        }
    }

    auto hrow = [&](float* hv, int r) {
        uvf4 a = *(const uvf4*)(M + r * MWs + s0);
        #pragma unroll
        for (int t = 0; t < 4; ++t)
            hv[t] = fmaf(W[t][0], a[0],
                    fmaf(W[t][1], a[1],
                    fmaf(W[t][2], a[2], W[t][3] * a[3])));
    };

    float* outm = out + OFF_MASKS + (size_t)bk * (THs * TWs);
    auto emit = [&](int row, float wA, const float* pA, float wB, const float* pB) {
        vf4 o;
        #pragma unroll
        for (int t = 0; t < 4; ++t) {
            float v = fmaf(wA, pA[t], wB * pB[t]);
            o[t] = (v > 0.0f) ? 1.0f : 0.0f;
        }
        __builtin_nontemporal_store(o, (vf4*)(outm + (size_t)row * TWs + 4 * c));
    };

    #pragma unroll
    for (int sc = 0; sc < 2; ++sc) {
        const int s  = sP + sc;
        const int Y0 = 80 * s + 20 * rs;   // first output row of this lane
        const int M0 = Y0 / 5;             // 16s + 4rs

        float hA[4], hB[4], hC[4], hD[4];
        hrow(hC, max(2 * M0 - 1, 0));
        hrow(hD, 2 * M0);

        #pragma unroll
        for (int g = 0; g < 4; ++g) {
            #pragma unroll
            for (int t = 0; t < 4; ++t) { hA[t] = hC[t]; hB[t] = hD[t]; }
            const int Mg = M0 + g;
            hrow(hC, 2 * Mg + 1);
            hrow(hD, min(2 * Mg + 2, MHs - 1));

            const int Y = Y0 + 5 * g;
            emit(Y + 0, 0.3f, hA, 0.7f, hB);   // phase 0: h[2m-1], h[2m]
            emit(Y + 1, 0.9f, hB, 0.1f, hC);   // phase 1: h[2m],  h[2m+1]
            emit(Y + 2, 0.5f, hB, 0.5f, hC);   // phase 2
            emit(Y + 3, 0.1f, hB, 0.9f, hC);   // phase 3
            emit(Y + 4, 0.7f, hC, 0.3f, hD);   // phase 4: h[2m+1], h[2m+2]
        }
    }
}

// ---------------------------------------------------------------------------
extern "C" void kernel_launch(void* const* d_in, const int* in_sizes, int n_in,
                              void* d_out, int out_size, void* d_ws, size_t ws_size,
                              hipStream_t stream) {
    const float* logits = (const float*)d_in[0];   // [B,Q,C]
    const float* boxes  = (const float*)d_in[1];   // [B,Q,4]
    const float* masks  = (const float*)d_in[2];   // [B,Q,128,128]
    const float* osz    = (const float*)d_in[3];   // [B,2]
    // d_in[4]/d_in[5] = target_h/target_w (constant 320, baked in)

    float* out = (float*)d_out;
    int* qidx  = (int*)d_ws;                       // B*K ints

    topk_kernel<<<Bq, TPB, 0, stream>>>(logits, boxes, osz, out, qidx);
    resize_kernel<<<Bq * Kn * 2, 320, 0, stream>>>(masks, qidx, out);
}